// Round 12
// baseline (82.234 us; speedup 1.0000x reference)
//
#include <hip/hip_runtime.h>
#include <math.h>

// BoundaryDistanceLoss — H=W=1024 binary masks (float 0/1).
// edges = seg - erode3x3(seg); exact EDT of edges; loss =
// sigmoid((mean(target_edges*pred_dt) + mean(pred_edges*target_dt))/2).
//
// R11->R12: kill the fused kernel's redundancy. 32-col tiles (64-col window,
// margin 16 >= row bound 9 -> exact iff D2 <= min(256, dl^2, dr^2)); ONE
// block serves BOTH images (their window rows coincide): stage both 146x64
// bit-windows once, run EDT(pred)*targ_edges then EDT(targ)*pred_edges
// reusing one hs buffer. Grid 256 blocks (1/CU), fetch ~19MB (was 72MB),
// same total EDT math. 2 nodes, no atomics/fences.
//
// ws layout: partial (1KB f32) only.

#define HW 1024
#define WIN 8
#define RPB 128
#define KROWS (RPB + 2 * WIN)   // 144
#define HS_STRIDE 33            // 32 cols + 1 pad
#define NR 146                  // staged rows per image: [i0-9, i0+137)
#define NBY (2 * NR * 16)       // 4672 staged float4-chunks (= LDS bytes)

// edge test straight from global seg (fallback only; zero-pad semantics)
__device__ inline int edge_at(const float* __restrict__ seg, int k, int j)
{
    if ((unsigned)k >= (unsigned)HW || (unsigned)j >= (unsigned)HW) return 0;
    if (seg[k * HW + j] == 0.f) return 0;
    bool all9 = true;
    #pragma unroll
    for (int dy = -1; dy <= 1; ++dy)
        #pragma unroll
        for (int dx = -1; dx <= 1; ++dx) {
            const int kk = k + dy, jj = j + dx;
            const float v = ((unsigned)kk < (unsigned)HW && (unsigned)jj < (unsigned)HW)
                            ? seg[kk * HW + jj] : 0.f;
            all9 = all9 && (v != 0.f);
        }
    return all9 ? 0 : 1;
}

// windowed row-pass: h = g^2 + kr^2 for 144 edge rows x 32 tile cols
__device__ __forceinline__ void fill_hs(float* __restrict__ hs,
                                        const unsigned long long* __restrict__ mm,
                                        int i0, int t)
{
    for (int idx = t; idx < 288; idx += 256) {
        const int tt = idx >> 1, half = idx & 1;
        const int kr = i0 - WIN + tt;
        float* __restrict__ hrow = &hs[tt * HS_STRIDE + half * 16];
        if ((unsigned)kr < (unsigned)HW) {
            const unsigned long long sA = mm[tt], sB = mm[tt + 1], sC = mm[tt + 2];
            const unsigned long long va = sA & sB & sC;
            const unsigned long long er = va & (va << 1) & (va >> 1);
            // bits 0/63 lack a col-neighbor: excluded as edges; any such miss
            // is >=16 cols from the tile -> covered by the 256 margin check
            const unsigned long long edge = (sB & ~er) & 0x7FFFFFFFFFFFFFFEull;
            const float krk = (float)(kr * kr);
            #pragma unroll
            for (int jc = 0; jc < 16; ++jc) {
                const int p = 16 + half * 16 + jc;          // p in [16,48)
                const unsigned long long mle = edge & ((1ull << (p + 1)) - 1ull);
                const unsigned long long mge = edge >> p;
                int g = 1 << 20;
                if (mle) g = p - (63 - __clzll((long long)mle));
                if (mge) g = min(g, __ffsll(mge) - 1);
                hrow[jc] = (g < (1 << 20)) ? fmaf((float)g, (float)g, krk) : 1e30f;
            }
        } else {
            #pragma unroll
            for (int jc = 0; jc < 16; ++jc) hrow[jc] = 1e30f;
        }
    }
}

// column EDT over the tile (windowed, exact) + weighted accumulate
__device__ __forceinline__ float edt_acc(const float* __restrict__ hs,
                                         const unsigned* __restrict__ esbw,
                                         int i0, int j0, int t,
                                         const float* __restrict__ segf)
{
    const int jj = t & 31;        // tile col
    const int iw = t >> 5;        // 0..7, each owns 16 rows
    float lsum = 0.f;

    #pragma unroll
    for (int g = 0; g < 4; ++g) {
        const int ib = i0 + iw * 16 + g * 4;     // 4 consecutive output rows
        const int kkS = iw * 16 + g * 4;         // = (ib-WIN) - (i0-WIN)
        float b0 = 3e38f, b1 = 3e38f, b2 = 3e38f, b3 = 3e38f;
        float kf = (float)(ib - WIN);
        const float m0 = -2.f * (float)(ib);
        const float m1 = -2.f * (float)(ib + 1);
        const float m2 = -2.f * (float)(ib + 2);
        const float m3 = -2.f * (float)(ib + 3);
        #pragma unroll
        for (int kk = kkS; kk < kkS + 2 * WIN + 4; ++kk) {
            const float hvv = hs[kk * HS_STRIDE + jj];
            b0 = fminf(b0, fmaf(m0, kf, hvv));
            b1 = fminf(b1, fmaf(m1, kf, hvv));
            b2 = fminf(b2, fmaf(m2, kf, hvv));
            b3 = fminf(b3, fmaf(m3, kf, hvv));
            kf += 1.f;
        }
        const int sLo = max(0, ib - WIN);
        const int sHi = min(HW - 1, ib + WIN + 3);
        float bs[4] = {b0, b1, b2, b3};
        #pragma unroll
        for (int w = 0; w < 4; ++w) {
            const int i = ib + w;
            float D2 = (float)(i * i) + bs[w];
            // exact iff no missed candidate can beat D2:
            //   col-window misses: dist^2 >= 16^2 = 256
            //   row-window misses: dist^2 >= dl^2 / dr^2
            const int dl = i - sLo + 1, dr = sHi + 1 - i;
            const bool need = (D2 > 256.f) ||
                              ((sLo > 0) && (D2 > (float)(dl * dl))) ||
                              ((sHi < HW - 1) && (D2 > (float)(dr * dr)));
            if (need) {  // statistically-dead exact fallback (global scan)
                const int jg = j0 + jj;
                float bb = 1e6f - (float)jg;     // empty-row/empty-image floor
                bb = bb * bb;
                for (int k = 0; k < HW; ++k) {
                    const float rowt = (float)((i - k) * (i - k));
                    if (rowt >= bb) continue;
                    for (int d = 0; d < HW; ++d) {
                        const float dd = rowt + (float)(d * d);
                        if (dd >= bb) break;
                        if (edge_at(segf, k, jg - d) || edge_at(segf, k, jg + d)) {
                            bb = dd; break;
                        }
                    }
                }
                D2 = bb;
            }
            const unsigned wbit = (esbw[i - i0] >> jj) & 1u;
            lsum += wbit ? sqrtf(D2) : 0.f;
        }
    }
    return lsum;
}

// ------------- Fused kernel: both images, windowed row-pass + EDT -----------
// grid (32 col-tiles, 8 row-chunks) = 256 blocks, block 256.
__global__ __launch_bounds__(256)
void k_main(const float* __restrict__ pred, const float* __restrict__ targ,
            float* __restrict__ partial)
{
    const int t  = threadIdx.x;
    const int j0 = blockIdx.x * 32;
    const int i0 = blockIdx.y * RPB;

    __shared__ alignas(16) unsigned char sbytes[NBY];
    __shared__ unsigned long long s_m[2 * NR];
    __shared__ float hs[KROWS * HS_STRIDE];
    __shared__ unsigned esb[2][RPB];
    __shared__ float wsum[4];

    // 64-col window: cols [W0, W0+64); tile at bits 16..47.
    // W0 = 32*bx - 16 is a multiple of 4 -> float4 chunks 16B-aligned.
    const int W0 = j0 - 16;

    // Phase 1: stage BOTH images' window bits as LDS nibble-bytes
    for (int idx = t; idx < NBY; idx += 256) {
        const int  img = idx >= NR * 16;
        const int  rel = img ? idx - NR * 16 : idx;
        const int  row = rel >> 4, c4 = rel & 15;
        const int  gr  = i0 - 9 + row;
        const int  c   = W0 + c4 * 4;
        float4 v = make_float4(0.f, 0.f, 0.f, 0.f);
        if ((unsigned)gr < (unsigned)HW && (unsigned)c <= 1020u) {
            const float* __restrict__ base = img ? targ : pred;
            v = *(const float4*)&base[gr * HW + c];
        }
        const unsigned by = (unsigned)(v.x != 0.f) | ((unsigned)(v.y != 0.f) << 1)
                          | ((unsigned)(v.z != 0.f) << 2) | ((unsigned)(v.w != 0.f) << 3);
        sbytes[idx] = (unsigned char)by;
    }
    __syncthreads();

    // Phase 2: pack each row's 16 nibble-bytes into one u64 mask
    for (int rowi = t; rowi < 2 * NR; rowi += 256) {
        const uint4 u = *(const uint4*)&sbytes[rowi * 16];
        const unsigned wq[4] = {u.x, u.y, u.z, u.w};
        unsigned long long r = 0ull;
        #pragma unroll
        for (int q = 0; q < 4; ++q) {
            const unsigned x = wq[q] & 0x0F0F0F0Fu;
            const unsigned y = x | (x >> 4);
            const unsigned h16 = (y & 0xFFu) | (((y >> 16) & 0xFFu) << 8);
            r |= (unsigned long long)h16 << (16 * q);
        }
        s_m[rowi] = r;
    }
    __syncthreads();

    // Phase 3: weight edge words for both images (rows [i0, i0+128)),
    //          and hs for image 0 (pred)
    {
        const int img = t >> 7, r = t & 127;
        const unsigned long long* mm = &s_m[img * NR];
        const unsigned long long sA = mm[r + 8], sB = mm[r + 9], sC = mm[r + 10];
        const unsigned long long va = sA & sB & sC;
        const unsigned long long er = va & (va << 1) & (va >> 1);
        const unsigned long long edge = sB & ~er;   // tile bits 16..47 valid
        esb[img][r] = (unsigned)((edge >> 16) & 0xFFFFFFFFull);
    }
    fill_hs(hs, &s_m[0], i0, t);        // image 0 (pred)
    __syncthreads();

    // Phase 4: EDT(pred) weighted by targ edges
    float lsum = edt_acc(hs, esb[1], i0, j0, t, pred);
    __syncthreads();                     // before hs reuse

    // Phase 5: hs for image 1 (targ), then EDT(targ) weighted by pred edges
    fill_hs(hs, &s_m[NR], i0, t);
    __syncthreads();
    lsum += edt_acc(hs, esb[0], i0, j0, t, targ);

    // reduce: wave shuffle then cross-wave via LDS; ONE plain store per block
    #pragma unroll
    for (int off = 32; off > 0; off >>= 1) lsum += __shfl_down(lsum, off);
    if ((t & 63) == 0) wsum[t >> 6] = lsum;
    __syncthreads();
    if (t == 0) {
        const int bid = blockIdx.x + 32 * blockIdx.y;   // 0..255
        partial[bid] = wsum[0] + wsum[1] + wsum[2] + wsum[3];
    }
}

// ---------------- Kernel C: reduce 256 partials + sigmoid ----------------
__global__ __launch_bounds__(256)
void k_fin(const float* __restrict__ partial, float* __restrict__ out)
{
    const int t = threadIdx.x;
    float s = partial[t];
    #pragma unroll
    for (int off = 32; off > 0; off >>= 1) s += __shfl_down(s, off);
    __shared__ float w[4];
    if ((t & 63) == 0) w[t >> 6] = s;
    __syncthreads();
    if (t == 0) {
        const float tot = w[0] + w[1] + w[2] + w[3];
        const float loss = tot * (1.f / (2.f * 1024.f * 1024.f));
        out[0] = 1.f / (1.f + expf(-loss));
    }
}

extern "C" void kernel_launch(void* const* d_in, const int* in_sizes, int n_in,
                              void* d_out, int out_size, void* d_ws, size_t ws_size,
                              hipStream_t stream)
{
    const float* preds   = (const float*)d_in[0];
    const float* targets = (const float*)d_in[1];
    float* out = (float*)d_out;

    float* partial = (float*)d_ws;   // 1 KB

    dim3 gM(HW / 32, HW / RPB, 1);   // 32 x 8 = 256 blocks
    k_main<<<gM, 256, 0, stream>>>(preds, targets, partial);

    k_fin<<<1, 256, 0, stream>>>(partial, out);
}

// Round 13
// 72.066 us; speedup vs baseline: 1.1411x; 1.1411x over previous
//
#include <hip/hip_runtime.h>
#include <math.h>

// BoundaryDistanceLoss — H=W=1024 binary masks (float 0/1).
// edges = seg - erode3x3(seg); exact EDT of edges; loss =
// sigmoid((mean(target_edges*pred_dt) + mean(pred_edges*target_dt))/2).
//
// R12->R13: fused kernel diagnosed VALU+latency bound (u64 bit math + staging
// iters), not fetch bound; R12's 1-block/CU killed latency hiding. Now:
// 16-col tiles with +-8-col margin -> 32-col U32 masks (1-instr clz/ffs,
// exact iff D2 <= min(64, dl^2, dr^2), same margin proof as R10-R12),
// 2208 staged chunks/block (half of R11), one image per block, 1024 blocks
// (4/CU). Weight rows staged from the other image. EDT core + fallback are
// the R10/R11 absmax=0.0 code verbatim. 2 nodes, no atomics/fences.
//
// ws layout: partial (4KB f32) only.

#define HW 1024
#define WIN 8
#define RPB 128
#define KROWS (RPB + 2 * WIN)   // 144
#define HS_STRIDE 17
#define NC 146                  // segc rows staged: [i0-9, i0+137)
#define NW 130                  // segw rows staged: [i0-1, i0+129)
#define NCHUNK ((NC + NW) * 8)  // 2208 float4 chunks (8 per 32-col row)

// edge test straight from global seg (fallback only; zero-pad semantics)
__device__ inline int edge_at(const float* __restrict__ seg, int k, int j)
{
    if ((unsigned)k >= (unsigned)HW || (unsigned)j >= (unsigned)HW) return 0;
    if (seg[k * HW + j] == 0.f) return 0;
    bool all9 = true;
    #pragma unroll
    for (int dy = -1; dy <= 1; ++dy)
        #pragma unroll
        for (int dx = -1; dx <= 1; ++dx) {
            const int kk = k + dy, jj = j + dx;
            const float v = ((unsigned)kk < (unsigned)HW && (unsigned)jj < (unsigned)HW)
                            ? seg[kk * HW + jj] : 0.f;
            all9 = all9 && (v != 0.f);
        }
    return all9 ? 0 : 1;
}

// ------------- Fused kernel: windowed row-pass + column EDT + partial -------
// grid (64 col-tiles, 8 row-chunks, 2 images) = 1024 blocks, block 256.
__global__ __launch_bounds__(256)
void k_main(const float* __restrict__ pred, const float* __restrict__ targ,
            float* __restrict__ partial)
{
    const int t  = threadIdx.x;
    const int j0 = blockIdx.x * 16;
    const int i0 = blockIdx.y * RPB;
    const int mc = blockIdx.z;
    const float* __restrict__ segc = mc ? targ : pred;   // image whose DT we take
    const float* __restrict__ segw = mc ? pred : targ;   // OTHER image (weights)

    __shared__ alignas(16) unsigned char sbytes[NCHUNK]; // 2208 nibble-bytes
    __shared__ unsigned s_m[NC + NW];                    // u32 row masks
    __shared__ float hs[KROWS * HS_STRIDE];
    __shared__ unsigned short esb[RPB];
    __shared__ float wsum[4];

    // 32-col window: cols [W0, W0+32); tile at bits 8..23.
    // W0 = 16*bx - 8 is a multiple of 4 -> float4 chunks 16B-aligned and
    // never straddle the image border.
    const int W0 = j0 - 8;

    // Phase 1: stage window bits as LDS nibble-bytes — independent float4
    // loads, full MLP, zero cross-lane ops. segc rows then segw rows.
    for (int idx = t; idx < NCHUNK; idx += 256) {
        const int  isW = idx >= NC * 8;
        const int  rel = isW ? idx - NC * 8 : idx;
        const int  row = rel >> 3, c4 = rel & 7;
        const int  gr  = isW ? (i0 - 1 + row) : (i0 - 9 + row);
        const int  c   = W0 + c4 * 4;
        float4 v = make_float4(0.f, 0.f, 0.f, 0.f);
        if ((unsigned)gr < (unsigned)HW && (unsigned)c <= 1020u) {
            const float* __restrict__ base = isW ? segw : segc;
            v = *(const float4*)&base[gr * HW + c];
        }
        const unsigned by = (unsigned)(v.x != 0.f) | ((unsigned)(v.y != 0.f) << 1)
                          | ((unsigned)(v.z != 0.f) << 2) | ((unsigned)(v.w != 0.f) << 3);
        sbytes[idx] = (unsigned char)by;
    }
    __syncthreads();

    // Phase 2: pack each row's 8 nibble-bytes into one u32 mask (pure bit ops)
    for (int rowi = t; rowi < NC + NW; rowi += 256) {
        const uint2 u = *(const uint2*)&sbytes[rowi * 8];
        unsigned r = 0;
        const unsigned wq[2] = {u.x, u.y};
        #pragma unroll
        for (int q = 0; q < 2; ++q) {
            const unsigned x = wq[q] & 0x0F0F0F0Fu;
            const unsigned y = x | (x >> 4);
            const unsigned h16 = (y & 0xFFu) | (((y >> 16) & 0xFFu) << 8);
            r |= h16 << (16 * q);
        }
        s_m[rowi] = r;
    }
    __syncthreads();

    // Phase 3a: weight edge words (other image), rows [i0, i0+128)
    if (t < RPB) {
        const unsigned sA = s_m[NC + t], sB = s_m[NC + t + 1], sC = s_m[NC + t + 2];
        const unsigned va = sA & sB & sC;
        const unsigned er = va & (va << 1) & (va >> 1);
        const unsigned edge = sB & ~er;          // tile bits 8..23 have valid nbrs
        esb[t] = (unsigned short)((edge >> 8) & 0xFFFFu);
    }
    // Phase 3b: windowed row-pass -> h = g^2 + kr^2 (threads 0..143, u32 ops)
    if (t < KROWS) {
        const int kr = i0 - WIN + t;             // edge row for hs row t
        float* __restrict__ hrow = &hs[t * HS_STRIDE];
        if ((unsigned)kr < (unsigned)HW) {
            const unsigned sA = s_m[t], sB = s_m[t + 1], sC = s_m[t + 2];
            const unsigned va = sA & sB & sC;
            const unsigned er = va & (va << 1) & (va >> 1);
            // bits 0/31 lack a col-neighbor: excluded as edge candidates; any
            // such miss is >=8 cols from the tile -> covered by the 64 check
            const unsigned edge = (sB & ~er) & 0x7FFFFFFEu;
            const float krk = (float)(kr * kr);
            #pragma unroll
            for (int jc = 0; jc < 16; ++jc) {
                const int p = 8 + jc;            // p in [8,24)
                const unsigned mle = edge & ((1u << (p + 1)) - 1u);
                const unsigned mge = edge >> p;
                int g = 1 << 20;
                if (mle) g = p - (31 - __clz(mle));
                if (mge) g = min(g, __ffs(mge) - 1);
                hrow[jc] = (g < (1 << 20)) ? fmaf((float)g, (float)g, krk) : 1e30f;
            }
        } else {
            #pragma unroll
            for (int jc = 0; jc < 16; ++jc) hrow[jc] = 1e30f;
        }
    }
    __syncthreads();

    // Phase 4: column EDT (windowed, exact) + weighted sum
    const int jj = t & 15;
    const int iw = t >> 4;   // 0..15, each owns 8 rows
    float lsum = 0.f;

    #pragma unroll
    for (int g = 0; g < 2; ++g) {
        const int ib = i0 + iw * 8 + g * 4;      // 4 consecutive output rows
        const int kkS = iw * 8 + g * 4;          // = (ib-WIN) - (i0-WIN)
        float b0 = 3e38f, b1 = 3e38f, b2 = 3e38f, b3 = 3e38f;
        float kf = (float)(ib - WIN);
        const float m0 = -2.f * (float)(ib);
        const float m1 = -2.f * (float)(ib + 1);
        const float m2 = -2.f * (float)(ib + 2);
        const float m3 = -2.f * (float)(ib + 3);
        #pragma unroll
        for (int kk = kkS; kk < kkS + 2 * WIN + 4; ++kk) {
            const float hvv = hs[kk * HS_STRIDE + jj];
            b0 = fminf(b0, fmaf(m0, kf, hvv));
            b1 = fminf(b1, fmaf(m1, kf, hvv));
            b2 = fminf(b2, fmaf(m2, kf, hvv));
            b3 = fminf(b3, fmaf(m3, kf, hvv));
            kf += 1.f;
        }
        const int sLo = max(0, ib - WIN);
        const int sHi = min(HW - 1, ib + WIN + 3);
        float bs[4] = {b0, b1, b2, b3};
        #pragma unroll
        for (int w = 0; w < 4; ++w) {
            const int i = ib + w;
            float D2 = (float)(i * i) + bs[w];
            // exact iff no missed candidate can beat D2:
            //   col-window misses: dist^2 >= 8^2 = 64
            //   row-window misses: dist^2 >= dl^2 / dr^2
            const int dl = i - sLo + 1, dr = sHi + 1 - i;
            const bool need = (D2 > 64.f) ||
                              ((sLo > 0) && (D2 > (float)(dl * dl))) ||
                              ((sHi < HW - 1) && (D2 > (float)(dr * dr)));
            if (need) {  // statistically-dead exact fallback (global scan)
                const int jg = j0 + jj;
                float bb = 1e6f - (float)jg;     // empty-row/empty-image floor
                bb = bb * bb;
                for (int k = 0; k < HW; ++k) {
                    const float rowt = (float)((i - k) * (i - k));
                    if (rowt >= bb) continue;
                    for (int d = 0; d < HW; ++d) {
                        const float dd = rowt + (float)(d * d);
                        if (dd >= bb) break;
                        if (edge_at(segc, k, jg - d) || edge_at(segc, k, jg + d)) {
                            bb = dd; break;
                        }
                    }
                }
                D2 = bb;
            }
            const unsigned wbit = (esb[i - i0] >> jj) & 1u;
            lsum += wbit ? sqrtf(D2) : 0.f;
        }
    }

    // reduce: wave shuffle then cross-wave via LDS; ONE plain store per block
    #pragma unroll
    for (int off = 32; off > 0; off >>= 1) lsum += __shfl_down(lsum, off);
    if ((t & 63) == 0) wsum[t >> 6] = lsum;
    __syncthreads();
    if (t == 0) {
        const int bid = blockIdx.x + 64 * (blockIdx.y + 8 * blockIdx.z);
        partial[bid] = wsum[0] + wsum[1] + wsum[2] + wsum[3];
    }
}

// ---------------- Kernel C: reduce 1024 partials + sigmoid ----------------
__global__ __launch_bounds__(256)
void k_fin(const float* __restrict__ partial, float* __restrict__ out)
{
    const int t = threadIdx.x;
    float s = partial[t] + partial[t + 256] + partial[t + 512] + partial[t + 768];
    #pragma unroll
    for (int off = 32; off > 0; off >>= 1) s += __shfl_down(s, off);
    __shared__ float w[4];
    if ((t & 63) == 0) w[t >> 6] = s;
    __syncthreads();
    if (t == 0) {
        const float tot = w[0] + w[1] + w[2] + w[3];
        const float loss = tot * (1.f / (2.f * 1024.f * 1024.f));
        out[0] = 1.f / (1.f + expf(-loss));
    }
}

extern "C" void kernel_launch(void* const* d_in, const int* in_sizes, int n_in,
                              void* d_out, int out_size, void* d_ws, size_t ws_size,
                              hipStream_t stream)
{
    const float* preds   = (const float*)d_in[0];
    const float* targets = (const float*)d_in[1];
    float* out = (float*)d_out;

    float* partial = (float*)d_ws;   // 4 KB

    dim3 gM(HW / 16, HW / RPB, 2);   // 64 x 8 x 2 = 1024 blocks
    k_main<<<gM, 256, 0, stream>>>(preds, targets, partial);

    k_fin<<<1, 256, 0, stream>>>(partial, out);
}